// Round 8
// baseline (463.793 us; speedup 1.0000x reference)
//
#include <hip/hip_runtime.h>
#include <hip/hip_bf16.h>

// Problem constants (B=2, D=64, H=W=96)
constexpr int B_    = 2;
constexpr int D_    = 64;
constexpr int N_    = 9216;      // 96*96
constexpr int ITERS = 4;

constexpr int MTQ     = 256;          // queries per workgroup (64/wave, 2 m-tiles)
constexpr int MBF     = N_ / MTQ;     // 36 m-blocks
constexpr int KS      = 9;            // key-split factor (atomics make KS free)
constexpr int KEYS_WG = N_ / KS;      // 1024 keys per workgroup
constexpr int KTILES  = KEYS_WG / 128;// 8 key tiles of 128
constexpr int NWG     = B_ * MBF * KS;// 648 flash workgroups (~2.5/CU)
constexpr int PB      = 144;          // prep n-blocks of 64
constexpr int CBM     = 128;          // combine m-tile
constexpr int CB      = N_ / CBM;     // 72 combine blocks per batch

constexpr float KBW  = 0.3f;
constexpr float STEP = 0.5f;
constexpr float C2   = 0.43280851226668905f;  // KBW * log2(e)

using short8   = __attribute__((ext_vector_type(8))) short;
using float16v = __attribute__((ext_vector_type(16))) float;
typedef __attribute__((ext_vector_type(2))) __bf16 bf16x2;

__device__ __forceinline__ unsigned short f2bf(float f) {
  union { float f; unsigned u; } v; v.f = f;
  unsigned u = v.u;
  unsigned r = (u + 0x7fffu + ((u >> 16) & 1u)) >> 16;   // RNE
  return (unsigned short)r;
}

#if __has_builtin(__builtin_amdgcn_cvt_pk_bf16_f32)
__device__ __forceinline__ unsigned pk2bf(float a, float b) {
  bf16x2 r = __builtin_amdgcn_cvt_pk_bf16_f32(a, b);   // low <- a, high <- b, RNE
  union { bf16x2 h; unsigned u; } v; v.h = r; return v.u;
}
#else
__device__ __forceinline__ unsigned pk2bf(float a, float b) {
  return (unsigned)f2bf(a) | ((unsigned)f2bf(b) << 16);
}
#endif

// cs += lo(u) + hi(u) for packed bf16 pair u — 1 instr via dot2.
__device__ __forceinline__ float csum2(unsigned u, float cs) {
#if __has_builtin(__builtin_amdgcn_fdot2_f32_bf16)
  union { unsigned x; bf16x2 h; } a, o;
  a.x = u; o.x = 0x3f803f80u;                          // (1.0, 1.0) bf16
  return __builtin_amdgcn_fdot2_f32_bf16(a.h, o.h, cs, false);
#else
  union { unsigned u; float f; } lo, hi;
  lo.u = u << 16; hi.u = u & 0xffff0000u;
  return cs + lo.f + hi.f;
#endif
}

// Async global->LDS DMA, 16 B/lane; lds_base wave-uniform, lane i -> base+16i.
__device__ __forceinline__ void dma16(const unsigned short* g,
                                      unsigned short* lds_base, int lane) {
#if __has_builtin(__builtin_amdgcn_global_load_lds)
  __builtin_amdgcn_global_load_lds(
      (const __attribute__((address_space(1))) unsigned int*)g,
      (__attribute__((address_space(3))) unsigned int*)lds_base, 16, 0, 0);
#else
  *(int4*)((char*)lds_base + lane * 16) = *(const int4*)g;
#endif
}

// ---------------------------------------------------------------------------
// prep: x_in (fp32 [b][d][n]) -> out slice 0 (copy), Xbf bf16 [b][d][n],
//       XT bf16 [b][n][d] (LDS transpose)
// ---------------------------------------------------------------------------
__global__ void prep_kernel(const float* __restrict__ xin, float* __restrict__ out,
                            unsigned short* __restrict__ XT,
                            unsigned short* __restrict__ Xbf)
{
  const int bx = blockIdx.x;
  const int nb = bx % PB, b = bx / PB;
  const int n0 = nb * 64;
  const int tid = threadIdx.x;
  __shared__ float tile[64 * 65];

  #pragma unroll
  for (int r = 0; r < 16; ++r) {
    int idx = r * 256 + tid;
    int d = idx >> 6, j = idx & 63;
    float v = xin[((size_t)b * 64 + d) * N_ + n0 + j];
    out[(((size_t)b * 5 + 0) * 64 + d) * N_ + n0 + j] = v;
    Xbf[((size_t)b * 64 + d) * N_ + n0 + j] = f2bf(v);
    tile[d * 65 + j] = v;
  }
  __syncthreads();
  #pragma unroll
  for (int r = 0; r < 16; ++r) {
    int idx = r * 256 + tid;
    int nl = idx >> 6, d = idx & 63;
    XT[((size_t)b * N_ + n0 + nl) * 64 + d] = f2bf(tile[d * 65 + nl]);
  }
}

// ---------------------------------------------------------------------------
// flash: wg = (b, 256-query m-block, 1/9 key-split). Wave w owns queries
// m0+w*64..+63 (2 m-tiles); all 4 waves share each staged 128-key tile, and
// af/b2 fragments are reused across the 2 m-tiles (halves per-query LDS
// traffic vs R7 — LDS pipe was 62% of makespan). (256,2): R6 proved this
// register shape spills at (256,3); 2 waves/EU gives a 256-reg budget.
//
// σ-TRICK (validated R6/R7): A-fragment reads key row σ(c) (bits 2<->3 of c
// swapped) -> exp'd weights land already in A-operand order. Queries
// pre-scaled by C2 -> w = exp2(S) directly. Colsum from ROUNDED weights
// (dot2 with ones) -> the 2.2e8 self-term cancels exactly in num/denom.
//
// KS-reduction via global fp32 atomicAdd into accG[b][n][d] / csG[b][n]
// (zeroed per iteration by hipMemsetAsync). Reorder noise ~1e-7 relative.
// ---------------------------------------------------------------------------
__global__ void __launch_bounds__(256, 2) flash_kernel(
    const unsigned short* __restrict__ XT,
    const unsigned short* __restrict__ Xbf,
    float* __restrict__ accG, float* __restrict__ csG)
{
  const int bx   = blockIdx.x;
  const int ks   = bx % KS;
  const int rest = bx / KS;
  const int mb   = rest % MBF;
  const int b    = rest / MBF;
  const int tid  = threadIdx.x;
  const int wave = tid >> 6, lane = tid & 63;
  const int c = lane & 31, h = lane >> 5;
  const int cp = (c & 0x13) | ((c & 4) << 1) | ((c & 8) >> 1);  // swap bits 2,3
  const int m0 = mb * MTQ;
  const int bpaddr = (lane ^ 32) << 2;      // ds_bpermute byte index (epilogue)

  const unsigned short* XTb = XT  + (size_t)b * N_ * 64;
  const unsigned short* Xb  = Xbf + (size_t)b * 64 * N_;

  __shared__ unsigned short sXT[128 * 64];  // [key][d], chunk-swizzled
  __shared__ unsigned short sXB[64 * 128];  // [d][n],  chunk-swizzled

  // wave's resident query fragments (B-operand), pre-scaled by C2
  short8 qf[2][4];
  #pragma unroll
  for (int mt = 0; mt < 2; ++mt)
    #pragma unroll
    for (int k = 0; k < 4; ++k) {
      short8 raw = *(const short8*)(XTb +
          (size_t)(m0 + wave * 64 + mt * 32 + c) * 64 + k * 16 + h * 8);
      unsigned o[4];
      const unsigned* rw = (const unsigned*)&raw;
      #pragma unroll
      for (int p4 = 0; p4 < 4; ++p4) {
        union { unsigned u; float f; } lo, hi;
        lo.u = rw[p4] << 16; hi.u = rw[p4] & 0xffff0000u;
        o[p4] = pk2bf(lo.f * C2, hi.f * C2);
      }
      qf[mt][k] = *(const short8*)o;
    }

  float16v zv;
  #pragma unroll
  for (int p = 0; p < 16; ++p) zv[p] = 0.f;
  float16v acc[2][2];
  acc[0][0] = zv; acc[0][1] = zv; acc[1][0] = zv; acc[1][1] = zv;
  float cs[2] = {0.f, 0.f};

  // DMA lane coords
  const int xt_rr = lane >> 3, xt_sc = lane & 7;   // 8 rows x 8 chunks
  const int xb_rr = lane >> 4, xb_sc = lane & 15;  // 4 rows x 16 chunks

  int n0g = ks * KEYS_WG;
  for (int t = 0; t < KTILES; ++t, n0g += 128) {
    __syncthreads();   // prior tile fully consumed
    // ---- DMA staging; swizzle on global side: LDS[row][sc] = chunk sc^(row&7)
    #pragma unroll
    for (int ii = 0; ii < 4; ++ii) {
      int row = wave * 32 + ii * 8 + xt_rr;                 // key row
      int gc  = xt_sc ^ (row & 7);
      dma16(XTb + (size_t)(n0g + row) * 64 + gc * 8,
            sXT + (wave * 32 + ii * 8) * 64, lane);
    }
    #pragma unroll
    for (int ii = 0; ii < 4; ++ii) {
      int row = wave * 16 + ii * 4 + xb_rr;                 // d row
      int gc  = xb_sc ^ (row & 7);
      dma16(Xb + (size_t)row * N_ + n0g + gc * 8,
            sXB + (wave * 16 + ii * 4) * 128, lane);
    }
    __syncthreads();   // tile ready

    #pragma unroll
    for (int s = 0; s < 4; ++s) {           // 4 key subtiles of 32
      // A-frags (keys, σ-permuted rows): row = s*32 + σ(c)
      short8 af[4];
      #pragma unroll
      for (int k = 0; k < 4; ++k)
        af[k] = *(const short8*)(sXT + (s * 32 + cp) * 64 +
                                 ((k * 2 + h) ^ (cp & 7)) * 8);
      // B-frags (X): row = dt*32+c, chunk = 4s + 2*k2 + h — shared by both mt
      short8 b20[2], b21[2];
      #pragma unroll
      for (int dt = 0; dt < 2; ++dt) {
        b20[dt] = *(const short8*)(sXB + (dt * 32 + c) * 128 + ((4 * s + h)     ^ (c & 7)) * 8);
        b21[dt] = *(const short8*)(sXB + (dt * 32 + c) * 128 + ((4 * s + 2 + h) ^ (c & 7)) * 8);
      }

      #pragma unroll
      for (int mt = 0; mt < 2; ++mt) {
        float16v S = zv;
        #pragma unroll
        for (int k = 0; k < 4; ++k)
          S = __builtin_amdgcn_mfma_f32_32x32x16_bf16(af[k], qf[mt][k], S, 0, 0, 0);

        // exp2 + packed bf16; colsum from the ROUNDED weights
        unsigned q[8];
        #pragma unroll
        for (int g = 0; g < 8; ++g) {
          float w0 = __builtin_amdgcn_exp2f(S[2 * g]);
          float w1 = __builtin_amdgcn_exp2f(S[2 * g + 1]);
          unsigned u = pk2bf(w0, w1);
          q[g] = u;
          cs[mt] = csum2(u, cs[mt]);
        }

        // σ-permute: q[] already A-operand ordered
        union { unsigned d[4]; short8 s; } a20, a21;
        a20.d[0] = q[0]; a20.d[1] = q[1]; a20.d[2] = q[2]; a20.d[3] = q[3];
        a21.d[0] = q[4]; a21.d[1] = q[5]; a21.d[2] = q[6]; a21.d[3] = q[7];

        #pragma unroll
        for (int dt = 0; dt < 2; ++dt)
          acc[mt][dt] = __builtin_amdgcn_mfma_f32_32x32x16_bf16(
              a20.s, b20[dt], acc[mt][dt], 0, 0, 0);
        #pragma unroll
        for (int dt = 0; dt < 2; ++dt)
          acc[mt][dt] = __builtin_amdgcn_mfma_f32_32x32x16_bf16(
              a21.s, b21[dt], acc[mt][dt], 0, 0, 0);
      }
    }
  }

  // -------- epilogue: KS-reduction via device-scope global atomics ---------
  #pragma unroll
  for (int mt = 0; mt < 2; ++mt) {
    union { float f; int i; } cu; cu.f = cs[mt];
    cu.i = __builtin_amdgcn_ds_bpermute(bpaddr, cu.i);
    float cst = cs[mt] + cu.f;
    if (h == 0)
      atomicAdd(&csG[(size_t)b * N_ + m0 + wave * 64 + mt * 32 + c], cst);
    #pragma unroll
    for (int dt = 0; dt < 2; ++dt)
      #pragma unroll
      for (int p = 0; p < 16; ++p) {
        int m = m0 + wave * 64 + mt * 32 + (p & 3) + 8 * (p >> 2) + 4 * h;
        atomicAdd(&accG[((size_t)b * N_ + m) * 64 + dt * 32 + c], acc[mt][dt][p]);
      }
  }
}

// ---------------------------------------------------------------------------
// combine: read accG/csG, normalize, blend with x_cur (= out slice t),
// write out slice t+1 + next iteration's Xbf / XT (bf16). grid: B_*CB.
// ---------------------------------------------------------------------------
__global__ void combine_kernel(const float* __restrict__ accG,
                               const float* __restrict__ csG,
                               float* __restrict__ out,
                               unsigned short* __restrict__ XT,
                               unsigned short* __restrict__ Xbf, int t)
{
  const int bx = blockIdx.x;
  const int mb = bx % CB, b = bx / CB;
  const int m0 = mb * CBM;
  const int tid = threadIdx.x;
  __shared__ float accs[128 * 65];
  __shared__ float cst[128];

  #pragma unroll
  for (int r = 0; r < 32; ++r) {
    int idx = r * 256 + tid;                  // m = idx>>6, d = idx&63
    accs[(idx >> 6) * 65 + (idx & 63)] =
        accG[((size_t)b * N_ + m0) * 64 + idx];
  }
  if (tid < 128) cst[tid] = csG[(size_t)b * N_ + m0 + tid];
  __syncthreads();

  #pragma unroll
  for (int r = 0; r < 32; ++r) {
    int idx = r * 256 + tid;
    int m = idx & 127, d = idx >> 7;          // m fastest -> coalesced global n
    float a = accs[m * 65 + d];
    size_t obase = (((size_t)b * 5 + t) * 64 + d) * N_ + m0 + m;
    float xc = out[obase];
    float v = STEP * (a / cst[m]) + (1.f - STEP) * xc;
    out[obase + (size_t)64 * N_] = v;         // slice t+1
    Xbf[((size_t)b * 64 + d) * N_ + m0 + m] = f2bf(v);
    accs[m * 65 + d] = v;                     // in-place for transpose pass
  }
  __syncthreads();

  #pragma unroll
  for (int r = 0; r < 32; ++r) {
    int idx = r * 256 + tid;
    int m = idx >> 6, d = idx & 63;           // d fastest -> coalesced XT row
    XT[((size_t)b * N_ + m0 + m) * 64 + d] = f2bf(accs[m * 65 + d]);
  }
}

// ---------------------------------------------------------------------------
extern "C" void kernel_launch(void* const* d_in, const int* in_sizes, int n_in,
                              void* d_out, int out_size, void* d_ws, size_t ws_size,
                              hipStream_t stream)
{
  (void)in_sizes; (void)n_in; (void)out_size; (void)ws_size;
  const float* xin = (const float*)d_in[0];
  float* out = (float*)d_out;
  char* ws = (char*)d_ws;

  // workspace layout (9,510,912 B total):
  unsigned short* XT   = (unsigned short*)(ws);            //  2,359,296 B
  unsigned short* Xbf  = (unsigned short*)(ws + 2359296);  //  2,359,296 B
  float*          accG = (float*)(ws + 4718592);           //  4,718,592 B
  float*          csG  = (float*)(ws + 9437184);           //     73,728 B

  prep_kernel<<<B_ * PB, 256, 0, stream>>>(xin, out, XT, Xbf);
  for (int t = 0; t < ITERS; ++t) {
    hipMemsetAsync(ws + 4718592, 0, 4718592 + 73728, stream);  // accG + csG
    flash_kernel<<<NWG, 256, 0, stream>>>(XT, Xbf, accG, csG);
    combine_kernel<<<B_ * CB, 256, 0, stream>>>(accG, csG, out, XT, Xbf, t);
  }
}